// Round 9
// baseline (2683.821 us; speedup 1.0000x reference)
//
#include <hip/hip_runtime.h>

typedef _Float16 f16;
typedef _Float16 f16x8 __attribute__((ext_vector_type(8)));
typedef float f32x4 __attribute__((ext_vector_type(4)));

#define B_ 4096
#define N_ 32768
#define D_ 1024
#define BM 64           // query rows per block (traffic = (B/BM)*N*D*4 bytes)
#define BN 128          // KV tile per iteration (16 cols per wave x 8 waves)
#define THREADS 512
#define DSLICE 128      // D columns owned per wave in PV

__device__ __forceinline__ f32x4 mfma16(f16x8 a, f16x8 b, f32x4 c) {
    return __builtin_amdgcn_mfma_f32_16x16x32_f16(a, b, c, 0, 0, 0);
}

// ---- convert K (fp32 -> f16, same layout) -----------------------------------
__global__ void conv_k16(const float* __restrict__ src, f16* __restrict__ dst) {
    size_t i = ((size_t)blockIdx.x * blockDim.x + threadIdx.x) * 8;
    const float4* s = (const float4*)(src + i);
    float4 a = s[0], b = s[1];
    f16x8 h;
    h[0] = (f16)a.x; h[1] = (f16)a.y; h[2] = (f16)a.z; h[3] = (f16)a.w;
    h[4] = (f16)b.x; h[5] = (f16)b.y; h[6] = (f16)b.z; h[7] = (f16)b.w;
    *(f16x8*)(dst + i) = h;
}

// ---- convert + transpose V: V[N][D] fp32 -> VT[D][N] f16 ---------------------
__global__ void conv_vt(const float* __restrict__ V, f16* __restrict__ VT) {
    __shared__ f16 tile[64][65];
    int n0 = blockIdx.x << 6, d0 = blockIdx.y << 6;
    for (int idx = threadIdx.x; idx < 4096; idx += 256) {
        int i = idx >> 6, j = idx & 63;
        tile[j][i] = (f16)V[(size_t)(n0 + i) * D_ + d0 + j];
    }
    __syncthreads();
    for (int idx = threadIdx.x; idx < 4096; idx += 256) {
        int j = idx >> 6, i = idx & 63;
        VT[(size_t)(d0 + j) * N_ + n0 + i] = tile[j][i];
    }
}

// ---- convert + tile-permute X: fp32 [B][D] -> f16, k-major per 64-row tile ---
// elem(bblk,row,d) -> Xp[bblk*65536 + (d>>5)*2048 + row*32 + ((d&31)>>3)*8 + (d&7)]
__global__ void conv_xp(const float* __restrict__ X, f16* __restrict__ Xp) {
    int idx = blockIdx.x * 256 + threadIdx.x;       // < B*D/8
    int b  = idx >> 7;
    int d0 = (idx & 127) << 3;
    const float4* s = (const float4*)(X + (size_t)b * D_ + d0);
    float4 a = s[0], c = s[1];
    f16x8 h;
    h[0] = (f16)a.x; h[1] = (f16)a.y; h[2] = (f16)a.z; h[3] = (f16)a.w;
    h[4] = (f16)c.x; h[5] = (f16)c.y; h[6] = (f16)c.z; h[7] = (f16)c.w;
    int bblk = b >> 6, row = b & 63, dblk = d0 >> 5, sub = (d0 & 31) >> 3;
    *(f16x8*)(Xp + (size_t)bblk * (BM * D_) + dblk * 2048 + row * 32 + sub * 8) = h;
}

// ---- main fused attention kernel --------------------------------------------
// k-major LDS (64 rows): byte_off(row,d) = (d>>5)*4096 + row*64
//                                        + ((d&31)>>3)*16 + (d&7)*2
// fragment read = base(l15,lg) + rg*1024 + ks*4096 (pure immediates),
// lane-consecutive 16B within each 4096B block -> conflict-free.
template<int NSPLIT>
__global__ __launch_bounds__(THREADS, 1)
void attn_main(const f16* __restrict__ Xp, const f16* __restrict__ Kh,
               const f16* __restrict__ VT, float* __restrict__ Opart,
               float* __restrict__ Mpart, float* __restrict__ Lpart)
{
    __shared__ __align__(16) f16 Xh[BM * D_];    // 128 KB, k-major
    __shared__ __align__(16) f16 Pl[BM * BN];    // 16 KB, k-major
    __shared__ float2 red[BM][9];                // 4.6 KB, pad 9 -> conflict-free

    const int NCHUNK = N_ / NSPLIT;
    const int ITERS  = NCHUNK / BN;

    const int bid = blockIdx.x;
    int chunk, bblk;
    if (NSPLIT == 4) {
        chunk = (bid & 7) >> 1;                       // chunk -> XCD pair
        bblk  = ((bid >> 3) << 1) | (bid & 1);        // 0..63 bijective
    } else {
        chunk = (bid & 7) >> 2;
        bblk  = ((bid >> 3) << 2) | (bid & 3);
    }
    const int kvbase = chunk * NCHUNK;
    const int b0 = bblk * BM;
    const int t  = threadIdx.x;

    // --- stage pre-permuted X tile: pure linear copy ---
    {
        const f16* xsrc = Xp + (size_t)bblk * (BM * D_);
        for (int c = t; c < BM * D_ / 8; c += THREADS)
            *(f16x8*)((char*)Xh + c * 16) = *(const f16x8*)(xsrc + c * 8);
    }
    __syncthreads();

    const int wave = t >> 6, lane = t & 63;
    const int l15 = lane & 15, lg = lane >> 4;

    // LDS read bases: + rg*1024 selects the 16-row group, + ks*4096 the k block
    const char* bhb = (const char*)Xh + l15 * 64 + lg * 16;
    const char* prb = (const char*)Pl + l15 * 64 + lg * 16;

    // K pointer: this wave's 16 KV rows, advancing BN rows/iter
    const f16* kp = Kh + (size_t)(kvbase + wave * 16 + l15) * D_ + lg * 8;
    // V base: this wave's D-slice rows in VT, advancing BN cols/iter
    const f16* vbase = VT + (size_t)(wave * DSLICE + l15) * N_ + kvbase + lg * 8;

    f32x4 S[4];
    auto QK = [&]() {
        #pragma unroll
        for (int rg = 0; rg < 4; ++rg) S[rg] = (f32x4){0.f, 0.f, 0.f, 0.f};
        #pragma unroll
        for (int kb = 0; kb < 8; ++kb) {
            f16x8 kf[4];
            #pragma unroll
            for (int j = 0; j < 4; ++j)
                kf[j] = *(const f16x8*)(kp + (kb * 4 + j) * 32);
            #pragma unroll
            for (int j = 0; j < 4; ++j) {
                int ks = kb * 4 + j;
                #pragma unroll
                for (int rg = 0; rg < 4; ++rg) {
                    f16x8 ah = *(const f16x8*)(bhb + rg * 1024 + ks * 4096);
                    S[rg] = mfma16(ah, kf[j], S[rg]);
                }
            }
        }
    };

    f32x4 O[4][8];
    #pragma unroll
    for (int rg = 0; rg < 4; ++rg)
        #pragma unroll
        for (int fn = 0; fn < 8; ++fn) O[rg][fn] = (f32x4){0.f, 0.f, 0.f, 0.f};
    float mq[16];
    #pragma unroll
    for (int u = 0; u < 16; ++u) mq[u] = -INFINITY;
    float m2[4], l2[4];
    #pragma unroll
    for (int v = 0; v < 4; ++v) { m2[v] = -INFINITY; l2[v] = 0.f; }

    QK();   // tile 0

    for (int it = 0; it < ITERS; ++it) {
        // ---- strip softmax over own 16 cols; publish P + {m,s} ----
        #pragma unroll
        for (int rg = 0; rg < 4; ++rg)
            #pragma unroll
            for (int i = 0; i < 4; ++i) {
                float v = S[rg][i];
                float mx = v;
                mx = fmaxf(mx, __shfl_xor(mx, 1));
                mx = fmaxf(mx, __shfl_xor(mx, 2));
                mx = fmaxf(mx, __shfl_xor(mx, 4));
                mx = fmaxf(mx, __shfl_xor(mx, 8));
                float p = __expf(v - mx);
                float s = p;
                s += __shfl_xor(s, 1);
                s += __shfl_xor(s, 2);
                s += __shfl_xor(s, 4);
                s += __shfl_xor(s, 8);
                int m = rg * 16 + lg * 4 + i;
                int off = (wave >> 1) * 4096 + m * 64
                        + ((wave & 1) * 2 + (l15 >> 3)) * 16 + ((l15 & 7) << 1);
                *(f16*)((char*)Pl + off) = (f16)p;
                if (l15 == 0) red[m][wave] = make_float2(mx, s);
            }
        __syncthreads();

        // ---- combine: per row-view (l15+16v): global max, l update ----
        #pragma unroll
        for (int v = 0; v < 4; ++v) {
            int row = l15 + 16 * v;
            float M2n = m2[v];
            #pragma unroll
            for (int s2 = 0; s2 < 8; ++s2)
                M2n = fmaxf(M2n, red[row][s2].x);
            float lsum = 0.f;
            #pragma unroll
            for (int s2 = 0; s2 < 8; ++s2) {
                float2 r2 = red[row][s2];
                lsum += __expf(r2.x - M2n) * r2.y;
            }
            l2[v] = l2[v] * __expf(m2[v] - M2n) + lsum;
            m2[v] = M2n;
        }

        // ---- q-view alpha via shfl; rescale O ----
        #pragma unroll
        for (int rg = 0; rg < 4; ++rg) {
            float al[4];
            #pragma unroll
            for (int i = 0; i < 4; ++i) {
                int src = (lane & 48) | (lg * 4 + i);
                float Mn = __shfl(m2[rg], src);
                al[i] = __expf(mq[rg * 4 + i] - Mn);
                mq[rg * 4 + i] = Mn;
            }
            #pragma unroll
            for (int fn = 0; fn < 8; ++fn)
                #pragma unroll
                for (int i = 0; i < 4; ++i)
                    O[rg][fn][i] *= al[i];
        }

        // ---- PV: O += (P * beta) x V; betas recomputed from red per ks2 ----
        #pragma unroll
        for (int ks2 = 0; ks2 < 4; ++ks2) {
            int strip = ks2 * 2 + (lg >> 1);
            f16x8 pa[4];
            #pragma unroll
            for (int rg = 0; rg < 4; ++rg) {
                f16 bt = (f16)__expf(red[l15 + 16 * rg][strip].x - m2[rg]);
                pa[rg] = *(const f16x8*)(prb + rg * 1024 + ks2 * 4096);
                #pragma unroll
                for (int j = 0; j < 8; ++j) pa[rg][j] *= bt;
            }
            #pragma unroll
            for (int fn = 0; fn < 8; ++fn) {
                f16x8 vv = *(const f16x8*)(vbase + (size_t)fn * (16 * N_) + ks2 * 32);
                #pragma unroll
                for (int rg = 0; rg < 4; ++rg)
                    O[rg][fn] = mfma16(pa[rg], vv, O[rg][fn]);
            }
        }

        // ---- advance, then next tile's QK before the closing barrier ----
        kp += (size_t)BN * D_;
        vbase += BN;
        if (it + 1 < ITERS) QK();
        __syncthreads();
    }

    // ---- epilogue: unnormalized O + per-row m/l partials ----
    float* Op = Opart + (size_t)chunk * B_ * D_;
    #pragma unroll
    for (int rg = 0; rg < 4; ++rg)
        #pragma unroll
        for (int fn = 0; fn < 8; ++fn)
            #pragma unroll
            for (int i = 0; i < 4; ++i) {
                int col = wave * DSLICE + fn * 16 + l15;
                int row = b0 + rg * 16 + lg * 4 + i;
                Op[(size_t)row * D_ + col] = O[rg][fn][i];
            }
    if (wave == 0 && lg == 0) {
        #pragma unroll
        for (int v = 0; v < 4; ++v) {
            Mpart[(size_t)chunk * B_ + b0 + 16 * v + l15] = m2[v];
            Lpart[(size_t)chunk * B_ + b0 + 16 * v + l15] = l2[v];
        }
    }
}

// ---- combine NSPLIT partials -------------------------------------------------
template<int NSPLIT>
__global__ void combine_k(const float* __restrict__ Opart,
                          const float* __restrict__ Mp, const float* __restrict__ Lp,
                          float* __restrict__ Outg)
{
    int b = blockIdx.x;
    float M = -INFINITY;
    #pragma unroll
    for (int c = 0; c < NSPLIT; ++c) M = fmaxf(M, Mp[(size_t)c * B_ + b]);
    float w[NSPLIT];
    float lsum = 0.f;
    #pragma unroll
    for (int c = 0; c < NSPLIT; ++c) {
        w[c] = __expf(Mp[(size_t)c * B_ + b] - M);
        lsum += w[c] * Lp[(size_t)c * B_ + b];
    }
    float inv = 1.f / lsum;
    float4* o = (float4*)(Outg + (size_t)b * D_);
    for (int i = threadIdx.x; i < D_ / 4; i += blockDim.x) {
        float4 r = make_float4(0.f, 0.f, 0.f, 0.f);
        #pragma unroll
        for (int c = 0; c < NSPLIT; ++c) {
            float4 a = ((const float4*)(Opart + ((size_t)c * B_ + b) * D_))[i];
            r.x += w[c] * a.x; r.y += w[c] * a.y;
            r.z += w[c] * a.z; r.w += w[c] * a.w;
        }
        r.x *= inv; r.y *= inv; r.z *= inv; r.w *= inv;
        o[i] = r;
    }
}

extern "C" void kernel_launch(void* const* d_in, const int* in_sizes, int n_in,
                              void* d_out, int out_size, void* d_ws, size_t ws_size,
                              hipStream_t stream) {
    const float* X = (const float*)d_in[0];
    const float* K = (const float*)d_in[1];
    const float* V = (const float*)d_in[2];
    float* Out = (float*)d_out;

    const size_t szKh = (size_t)N_ * D_ * sizeof(f16);   // 64 MiB
    const size_t szVT = (size_t)N_ * D_ * sizeof(f16);   // 64 MiB
    const size_t szXp = (size_t)B_ * D_ * sizeof(f16);   // 8 MiB
    const size_t szOp4 = 4ull * B_ * D_ * sizeof(float); // 64 MiB
    const size_t szM4  = 4ull * B_ * sizeof(float);

    f16*   Kh = (f16*)d_ws;
    f16*   VT = (f16*)((char*)d_ws + szKh);
    f16*   Xp = (f16*)((char*)d_ws + szKh + szVT);
    float* Op = (float*)((char*)d_ws + szKh + szVT + szXp);
    float* Mp = (float*)((char*)Op + szOp4);
    float* Lp = (float*)((char*)Mp + szM4);

    const size_t need4 = szKh + szVT + szXp + szOp4 + 2 * szM4;

    conv_k16<<<(N_ * D_ / 8) / 256, 256, 0, stream>>>(K, Kh);
    conv_vt<<<dim3(N_ / 64, D_ / 64), 256, 0, stream>>>(V, VT);
    conv_xp<<<(B_ * D_ / 8) / 256, 256, 0, stream>>>(X, Xp);

    if (ws_size >= need4) {
        attn_main<4><<<(B_ / BM) * 4, THREADS, 0, stream>>>(Xp, Kh, VT, Op, Mp, Lp);
        combine_k<4><<<B_, 256, 0, stream>>>(Op, Mp, Lp, Out);
    } else {
        attn_main<2><<<(B_ / BM) * 2, THREADS, 0, stream>>>(Xp, Kh, VT, Op, Mp, Lp);
        combine_k<2><<<B_, 256, 0, stream>>>(Op, Mp, Lp, Out);
    }
}

// Round 10
// 2677.522 us; speedup vs baseline: 1.0024x; 1.0024x over previous
//
#include <hip/hip_runtime.h>

typedef _Float16 f16;
typedef _Float16 f16x8 __attribute__((ext_vector_type(8)));
typedef float f32x4 __attribute__((ext_vector_type(4)));

#define B_ 4096
#define N_ 32768
#define D_ 1024
#define BM 64           // query rows per block (L3 traffic = (B/BM)*N*D*4 bytes)
#define BN 128          // KV tile per iteration (16 cols per wave x 8 waves)
#define THREADS 512
#define DSLICE 128      // D columns owned per wave in PV

__device__ __forceinline__ f32x4 mfma16(f16x8 a, f16x8 b, f32x4 c) {
    return __builtin_amdgcn_mfma_f32_16x16x32_f16(a, b, c, 0, 0, 0);
}

// ---- convert K (fp32 -> f16, same layout) -----------------------------------
__global__ void conv_k16(const float* __restrict__ src, f16* __restrict__ dst) {
    size_t i = ((size_t)blockIdx.x * blockDim.x + threadIdx.x) * 8;
    const float4* s = (const float4*)(src + i);
    float4 a = s[0], b = s[1];
    f16x8 h;
    h[0] = (f16)a.x; h[1] = (f16)a.y; h[2] = (f16)a.z; h[3] = (f16)a.w;
    h[4] = (f16)b.x; h[5] = (f16)b.y; h[6] = (f16)b.z; h[7] = (f16)b.w;
    *(f16x8*)(dst + i) = h;
}

// ---- convert + transpose V: V[N][D] fp32 -> VT[D][N] f16 ---------------------
__global__ void conv_vt(const float* __restrict__ V, f16* __restrict__ VT) {
    __shared__ f16 tile[64][65];
    int n0 = blockIdx.x << 6, d0 = blockIdx.y << 6;
    for (int idx = threadIdx.x; idx < 4096; idx += 256) {
        int i = idx >> 6, j = idx & 63;
        tile[j][i] = (f16)V[(size_t)(n0 + i) * D_ + d0 + j];
    }
    __syncthreads();
    for (int idx = threadIdx.x; idx < 4096; idx += 256) {
        int j = idx >> 6, i = idx & 63;
        VT[(size_t)(d0 + j) * N_ + n0 + i] = tile[j][i];
    }
}

// ---- convert + tile-permute X: fp32 [B][D] -> f16, k-major per 64-row tile ---
__global__ void conv_xp(const float* __restrict__ X, f16* __restrict__ Xp) {
    int idx = blockIdx.x * 256 + threadIdx.x;       // < B*D/8
    int b  = idx >> 7;
    int d0 = (idx & 127) << 3;
    const float4* s = (const float4*)(X + (size_t)b * D_ + d0);
    float4 a = s[0], c = s[1];
    f16x8 h;
    h[0] = (f16)a.x; h[1] = (f16)a.y; h[2] = (f16)a.z; h[3] = (f16)a.w;
    h[4] = (f16)c.x; h[5] = (f16)c.y; h[6] = (f16)c.z; h[7] = (f16)c.w;
    int bblk = b >> 6, row = b & 63, dblk = d0 >> 5, sub = (d0 & 31) >> 3;
    *(f16x8*)(Xp + (size_t)bblk * (BM * D_) + dblk * 2048 + row * 32 + sub * 8) = h;
}

// ---- main fused attention kernel --------------------------------------------
// k-major LDS (64 rows): byte_off(row,d) = (d>>5)*4096 + row*64
//                                        + ((d&31)>>3)*16 + (d&7)*2
// fragment read = base(l15,lg) + rg*1024 + ks*4096 (pure immediates),
// lane-consecutive 16B within each 4096B block -> conflict-free.
// amdgpu_waves_per_eu(2,2): pin allocator target to 2 waves/EU -> 256-VGPR
// budget, so the ~190-reg body (O[4][8]=128) fits with ZERO spill. The LDS
// (148.5 KB -> 1 block/CU) already limits occupancy to 2 waves/EU anyway.
template<int NSPLIT>
__global__
__attribute__((amdgpu_flat_work_group_size(THREADS, THREADS), amdgpu_waves_per_eu(2, 2)))
void attn_main(const f16* __restrict__ Xp, const f16* __restrict__ Kh,
               const f16* __restrict__ VT, float* __restrict__ Opart,
               float* __restrict__ Mpart, float* __restrict__ Lpart)
{
    __shared__ __align__(16) f16 Xh[BM * D_];    // 128 KB, k-major
    __shared__ __align__(16) f16 Pl[BM * BN];    // 16 KB, k-major
    __shared__ float2 red[BM][9];                // 4.6 KB, pad 9 -> conflict-free

    const int NCHUNK = N_ / NSPLIT;
    const int ITERS  = NCHUNK / BN;

    const int bid = blockIdx.x;
    int chunk, bblk;
    if (NSPLIT == 4) {
        chunk = (bid & 7) >> 1;                       // chunk -> XCD pair
        bblk  = ((bid >> 3) << 1) | (bid & 1);        // 0..63 bijective
    } else {
        chunk = (bid & 7) >> 2;
        bblk  = ((bid >> 3) << 2) | (bid & 3);
    }
    const int kvbase = chunk * NCHUNK;
    const int b0 = bblk * BM;
    const int t  = threadIdx.x;

    // --- stage pre-permuted X tile: pure linear copy ---
    {
        const f16* xsrc = Xp + (size_t)bblk * (BM * D_);
        for (int c = t; c < BM * D_ / 8; c += THREADS)
            *(f16x8*)((char*)Xh + c * 16) = *(const f16x8*)(xsrc + c * 8);
    }
    __syncthreads();

    const int wave = t >> 6, lane = t & 63;
    const int l15 = lane & 15, lg = lane >> 4;

    // LDS read bases: + rg*1024 selects the 16-row group, + ks*4096 the k block
    const char* bhb = (const char*)Xh + l15 * 64 + lg * 16;
    const char* prb = (const char*)Pl + l15 * 64 + lg * 16;

    // K pointer: this wave's 16 KV rows, advancing BN rows/iter
    const f16* kp = Kh + (size_t)(kvbase + wave * 16 + l15) * D_ + lg * 8;
    // V base: this wave's D-slice rows in VT, advancing BN cols/iter
    const f16* vbase = VT + (size_t)(wave * DSLICE + l15) * N_ + kvbase + lg * 8;

    f32x4 S[4];
    auto QK = [&]() {
        #pragma unroll
        for (int rg = 0; rg < 4; ++rg) S[rg] = (f32x4){0.f, 0.f, 0.f, 0.f};
        #pragma unroll
        for (int kb = 0; kb < 8; ++kb) {
            f16x8 kf[4];
            #pragma unroll
            for (int j = 0; j < 4; ++j)
                kf[j] = *(const f16x8*)(kp + (kb * 4 + j) * 32);
            #pragma unroll
            for (int j = 0; j < 4; ++j) {
                int ks = kb * 4 + j;
                #pragma unroll
                for (int rg = 0; rg < 4; ++rg) {
                    f16x8 ah = *(const f16x8*)(bhb + rg * 1024 + ks * 4096);
                    S[rg] = mfma16(ah, kf[j], S[rg]);
                }
            }
        }
    };

    f32x4 O[4][8];
    #pragma unroll
    for (int rg = 0; rg < 4; ++rg)
        #pragma unroll
        for (int fn = 0; fn < 8; ++fn) O[rg][fn] = (f32x4){0.f, 0.f, 0.f, 0.f};
    float mq[16];
    #pragma unroll
    for (int u = 0; u < 16; ++u) mq[u] = -INFINITY;
    float m2[4], l2[4];
    #pragma unroll
    for (int v = 0; v < 4; ++v) { m2[v] = -INFINITY; l2[v] = 0.f; }

    QK();   // tile 0

    for (int it = 0; it < ITERS; ++it) {
        // ---- strip softmax over own 16 cols; publish P + {m,s} ----
        #pragma unroll
        for (int rg = 0; rg < 4; ++rg)
            #pragma unroll
            for (int i = 0; i < 4; ++i) {
                float v = S[rg][i];
                float mx = v;
                mx = fmaxf(mx, __shfl_xor(mx, 1));
                mx = fmaxf(mx, __shfl_xor(mx, 2));
                mx = fmaxf(mx, __shfl_xor(mx, 4));
                mx = fmaxf(mx, __shfl_xor(mx, 8));
                float p = __expf(v - mx);
                float s = p;
                s += __shfl_xor(s, 1);
                s += __shfl_xor(s, 2);
                s += __shfl_xor(s, 4);
                s += __shfl_xor(s, 8);
                int m = rg * 16 + lg * 4 + i;
                int off = (wave >> 1) * 4096 + m * 64
                        + ((wave & 1) * 2 + (l15 >> 3)) * 16 + ((l15 & 7) << 1);
                *(f16*)((char*)Pl + off) = (f16)p;
                if (l15 == 0) red[m][wave] = make_float2(mx, s);
            }
        __syncthreads();

        // ---- combine: per row-view (l15+16v): global max, l update ----
        #pragma unroll
        for (int v = 0; v < 4; ++v) {
            int row = l15 + 16 * v;
            float M2n = m2[v];
            #pragma unroll
            for (int s2 = 0; s2 < 8; ++s2)
                M2n = fmaxf(M2n, red[row][s2].x);
            float lsum = 0.f;
            #pragma unroll
            for (int s2 = 0; s2 < 8; ++s2) {
                float2 r2 = red[row][s2];
                lsum += __expf(r2.x - M2n) * r2.y;
            }
            l2[v] = l2[v] * __expf(m2[v] - M2n) + lsum;
            m2[v] = M2n;
        }

        // ---- q-view alpha via shfl; rescale O ----
        #pragma unroll
        for (int rg = 0; rg < 4; ++rg) {
            float al[4];
            #pragma unroll
            for (int i = 0; i < 4; ++i) {
                int src = (lane & 48) | (lg * 4 + i);
                float Mn = __shfl(m2[rg], src);
                al[i] = __expf(mq[rg * 4 + i] - Mn);
                mq[rg * 4 + i] = Mn;
            }
            #pragma unroll
            for (int fn = 0; fn < 8; ++fn)
                #pragma unroll
                for (int i = 0; i < 4; ++i)
                    O[rg][fn][i] *= al[i];
        }

        // ---- PV: O += (P * beta) x V; betas recomputed from red per ks2 ----
        #pragma unroll
        for (int ks2 = 0; ks2 < 4; ++ks2) {
            int strip = ks2 * 2 + (lg >> 1);
            f16x8 pa[4];
            #pragma unroll
            for (int rg = 0; rg < 4; ++rg) {
                f16 bt = (f16)__expf(red[l15 + 16 * rg][strip].x - m2[rg]);
                pa[rg] = *(const f16x8*)(prb + rg * 1024 + ks2 * 4096);
                #pragma unroll
                for (int j = 0; j < 8; ++j) pa[rg][j] *= bt;
            }
            #pragma unroll
            for (int fn = 0; fn < 8; ++fn) {
                f16x8 vv = *(const f16x8*)(vbase + (size_t)fn * (16 * N_) + ks2 * 32);
                #pragma unroll
                for (int rg = 0; rg < 4; ++rg)
                    O[rg][fn] = mfma16(pa[rg], vv, O[rg][fn]);
            }
        }

        // ---- advance, then next tile's QK before the closing barrier ----
        kp += (size_t)BN * D_;
        vbase += BN;
        if (it + 1 < ITERS) QK();
        __syncthreads();
    }

    // ---- epilogue: unnormalized O + per-row m/l partials ----
    float* Op = Opart + (size_t)chunk * B_ * D_;
    #pragma unroll
    for (int rg = 0; rg < 4; ++rg)
        #pragma unroll
        for (int fn = 0; fn < 8; ++fn)
            #pragma unroll
            for (int i = 0; i < 4; ++i) {
                int col = wave * DSLICE + fn * 16 + l15;
                int row = b0 + rg * 16 + lg * 4 + i;
                Op[(size_t)row * D_ + col] = O[rg][fn][i];
            }
    if (wave == 0 && lg == 0) {
        #pragma unroll
        for (int v = 0; v < 4; ++v) {
            Mpart[(size_t)chunk * B_ + b0 + 16 * v + l15] = m2[v];
            Lpart[(size_t)chunk * B_ + b0 + 16 * v + l15] = l2[v];
        }
    }
}

// ---- combine NSPLIT partials -------------------------------------------------
template<int NSPLIT>
__global__ void combine_k(const float* __restrict__ Opart,
                          const float* __restrict__ Mp, const float* __restrict__ Lp,
                          float* __restrict__ Outg)
{
    int b = blockIdx.x;
    float M = -INFINITY;
    #pragma unroll
    for (int c = 0; c < NSPLIT; ++c) M = fmaxf(M, Mp[(size_t)c * B_ + b]);
    float w[NSPLIT];
    float lsum = 0.f;
    #pragma unroll
    for (int c = 0; c < NSPLIT; ++c) {
        w[c] = __expf(Mp[(size_t)c * B_ + b] - M);
        lsum += w[c] * Lp[(size_t)c * B_ + b];
    }
    float inv = 1.f / lsum;
    float4* o = (float4*)(Outg + (size_t)b * D_);
    for (int i = threadIdx.x; i < D_ / 4; i += blockDim.x) {
        float4 r = make_float4(0.f, 0.f, 0.f, 0.f);
        #pragma unroll
        for (int c = 0; c < NSPLIT; ++c) {
            float4 a = ((const float4*)(Opart + ((size_t)c * B_ + b) * D_))[i];
            r.x += w[c] * a.x; r.y += w[c] * a.y;
            r.z += w[c] * a.z; r.w += w[c] * a.w;
        }
        r.x *= inv; r.y *= inv; r.z *= inv; r.w *= inv;
        o[i] = r;
    }
}

extern "C" void kernel_launch(void* const* d_in, const int* in_sizes, int n_in,
                              void* d_out, int out_size, void* d_ws, size_t ws_size,
                              hipStream_t stream) {
    const float* X = (const float*)d_in[0];
    const float* K = (const float*)d_in[1];
    const float* V = (const float*)d_in[2];
    float* Out = (float*)d_out;

    const size_t szKh = (size_t)N_ * D_ * sizeof(f16);   // 64 MiB
    const size_t szVT = (size_t)N_ * D_ * sizeof(f16);   // 64 MiB
    const size_t szXp = (size_t)B_ * D_ * sizeof(f16);   // 8 MiB
    const size_t szOp4 = 4ull * B_ * D_ * sizeof(float); // 64 MiB
    const size_t szM4  = 4ull * B_ * sizeof(float);

    f16*   Kh = (f16*)d_ws;
    f16*   VT = (f16*)((char*)d_ws + szKh);
    f16*   Xp = (f16*)((char*)d_ws + szKh + szVT);
    float* Op = (float*)((char*)d_ws + szKh + szVT + szXp);
    float* Mp = (float*)((char*)Op + szOp4);
    float* Lp = (float*)((char*)Mp + szM4);

    const size_t need4 = szKh + szVT + szXp + szOp4 + 2 * szM4;

    conv_k16<<<(N_ * D_ / 8) / 256, 256, 0, stream>>>(K, Kh);
    conv_vt<<<dim3(N_ / 64, D_ / 64), 256, 0, stream>>>(V, VT);
    conv_xp<<<(B_ * D_ / 8) / 256, 256, 0, stream>>>(X, Xp);

    if (ws_size >= need4) {
        attn_main<4><<<(B_ / BM) * 4, THREADS, 0, stream>>>(Xp, Kh, VT, Op, Mp, Lp);
        combine_k<4><<<B_, 256, 0, stream>>>(Op, Mp, Lp, Out);
    } else {
        attn_main<2><<<(B_ / BM) * 2, THREADS, 0, stream>>>(Xp, Kh, VT, Op, Mp, Lp);
        combine_k<2><<<B_, 256, 0, stream>>>(Op, Mp, Lp, Out);
    }
}